// Round 15
// baseline (287.969 us; speedup 1.0000x reference)
//
#include <hip/hip_runtime.h>
#include <hip/hip_bf16.h>
#include <cstdint>
#include <cstddef>
#include <type_traits>

#define INTER 2816

typedef __bf16 bf16x8 __attribute__((ext_vector_type(8)));
typedef float f32x4 __attribute__((ext_vector_type(4)));
typedef unsigned short u16x8 __attribute__((ext_vector_type(8)));
using bf16 = __hip_bfloat16;
using u16 = unsigned short;

__device__ __forceinline__ u16 f2bu(float f) {
  bf16 h = __float2bfloat16(f);
  return *reinterpret_cast<u16*>(&h);
}
__device__ __forceinline__ float bu2f(u16 u) {
  bf16 h = *reinterpret_cast<bf16*>(&u);
  return __bfloat162float(h);
}

// Async global->LDS DMA, 16 B per lane (wave-uniform base + lane*16).
__device__ __forceinline__ void async16(const u16* g, u16* l) {
  __builtin_amdgcn_global_load_lds(
      (const __attribute__((address_space(1))) unsigned int*)g,
      (__attribute__((address_space(3))) unsigned int*)l, 16, 0, 0);
}

// Stage 8 contiguous f32 as bf16 (16B out).
__device__ __forceinline__ void stage8(u16* dst, const float* src) {
  const float4 a = *(const float4*)(src);
  const float4 b = *(const float4*)(src + 4);
  u16 tmp[8] = {f2bu(a.x), f2bu(a.y), f2bu(a.z), f2bu(a.w),
                f2bu(b.x), f2bu(b.y), f2bu(b.z), f2bu(b.w)};
  *(uint4*)dst = *(uint4*)tmp;
}

// ---------------------------------------------------------------------------
// Fused one-shot prep: f32->bf16 conversion of x/wgu/wd + weight repacks.
// wm2: 64 x INTER bf16 (63 metric rows + 1 zero pad). cwb: 9 x INTER bf16.
// ---------------------------------------------------------------------------
__global__ __launch_bounds__(256)
void prep_all(const float* __restrict__ x, const float* __restrict__ wgu,
              const float* __restrict__ wd, const float* __restrict__ w_metric,
              const float* __restrict__ conv_w, u16* __restrict__ xbf,
              u16* __restrict__ wgubf, u16* __restrict__ wdbf,
              u16* __restrict__ wm2, u16* __restrict__ cwb) {
  constexpr size_t S0 = (size_t)2048 * 1024;
  constexpr size_t S1 = (size_t)5632 * 1024;
  constexpr size_t S2 = (size_t)1024 * 2816;
  constexpr size_t NCONV_THREADS = (S0 + S1 + S2) / 8;  // 1343488 = 5248 blks
  const size_t t = (size_t)blockIdx.x * 256 + threadIdx.x;
  if (t < NCONV_THREADS) {
    const size_t e0 = t * 8;
    const float* src;
    u16* dst;
    size_t off;
    if (e0 < S0) {
      src = x; dst = xbf; off = e0;
    } else if (e0 < S0 + S1) {
      src = wgu; dst = wgubf; off = e0 - S0;
    } else {
      src = wd; dst = wdbf; off = e0 - S0 - S1;
    }
    stage8(dst + off, src + off);
  } else {
    const unsigned p = (unsigned)(t - NCONV_THREADS);  // 0..205567 (73 rows)
    const unsigned y = p / 2816u;                      // 0..72
    const unsigned c = p - y * 2816u;
    if (y < 64) {
      float v = 0.f;
      if (y < 63) {
        const unsigned o = y / 9, tap = y - o * 9;
        v = w_metric[((size_t)o * INTER + c) * 9 + tap];
      }
      wm2[(size_t)y * INTER + c] = f2bu(v);
    } else {
      const unsigned k = y - 64;
      cwb[(size_t)k * INTER + c] = f2bu(conv_w[(size_t)c * 9 + k]);
    }
  }
}

// ---------------------------------------------------------------------------
// NT GEMM, 128xBN tile, BK=64 staged as two BK=32 half-tiles (single buffer,
// one barrier-pair per 64 K-elements). 4 waves (2m x 2n), 16x16x32 mfma.
// NSWAP puts the n-tile on blockIdx.x for XCD pinning of B. Split-K via
// grid.z writes partial C at z*M*ldc. K must be a multiple of 64.
// ---------------------------------------------------------------------------
template <int BN, bool NSWAP, typename OT>
__global__ __launch_bounds__(256, 3)
void gemm_nt(const u16* __restrict__ A, int lda, const u16* __restrict__ Bt,
             int ldb, OT* __restrict__ C, int M, int ldc, int K) {
  constexpr int NJ = BN / 32;      // j-tiles per wave
  constexpr int BHALF = BN * 32;   // u16 per B half-tile
  __shared__ u16 As[2 * 128 * 32];
  __shared__ u16 Bs[2 * BHALF];
  const size_t koff = (size_t)blockIdx.z * K;
  A += koff;
  Bt += koff;
  C += (size_t)blockIdx.z * M * ldc;
  const int m0 = (NSWAP ? blockIdx.y : blockIdx.x) * 128;
  const int n0 = (NSWAP ? blockIdx.x : blockIdx.y) * BN;
  const int tid = threadIdx.x;
  const int lane = tid & 63;
  const int wv = tid >> 6;
  const int wm = wv & 1, wn = wv >> 1;
  const int lr = lane & 15;
  const int lq = lane >> 4;

  f32x4 acc[4][NJ];
#pragma unroll
  for (int i = 0; i < 4; ++i)
#pragma unroll
    for (int j = 0; j < NJ; ++j) acc[i][j] = (f32x4){0.f, 0.f, 0.f, 0.f};

  const int srow = tid >> 2;
  const int scol = (tid & 3) * 8;
  const u16* gA0 = A + (size_t)(m0 + srow) * lda + scol;
  const u16* gA1 = A + (size_t)(m0 + 64 + srow) * lda + scol;
  const u16* gB0 = Bt + (size_t)(n0 + srow) * ldb + scol;
  const u16* gB1 = Bt + (size_t)(n0 + 64 + srow) * ldb + scol;  // BN==128 only

  for (int kb = 0; kb < K; kb += 64) {
#pragma unroll
    for (int h = 0; h < 2; ++h) {
      const int kh = kb + h * 32;
      async16(gA0 + kh, As + h * 4096 + tid * 8);
      async16(gA1 + kh, As + h * 4096 + 2048 + tid * 8);
      async16(gB0 + kh, Bs + h * BHALF + tid * 8);
      if constexpr (BN == 128) async16(gB1 + kh, Bs + h * BHALF + 2048 + tid * 8);
    }
    __syncthreads();
#pragma unroll
    for (int h = 0; h < 2; ++h) {
      bf16x8 af[4], bfr[NJ];
#pragma unroll
      for (int i = 0; i < 4; ++i)
        af[i] = *(const bf16x8*)(&As[h * 4096 + (wm * 64 + i * 16 + lr) * 32 + lq * 8]);
#pragma unroll
      for (int j = 0; j < NJ; ++j)
        bfr[j] = *(const bf16x8*)(&Bs[h * BHALF + (wn * (BN / 2) + j * 16 + lr) * 32 + lq * 8]);
#pragma unroll
      for (int i = 0; i < 4; ++i)
#pragma unroll
        for (int j = 0; j < NJ; ++j)
          acc[i][j] = __builtin_amdgcn_mfma_f32_16x16x32_bf16(af[i], bfr[j],
                                                              acc[i][j], 0, 0, 0);
    }
    __syncthreads();
  }

#pragma unroll
  for (int i = 0; i < 4; ++i)
#pragma unroll
    for (int j = 0; j < NJ; ++j) {
      const int col = n0 + wn * (BN / 2) + j * 16 + lr;
#pragma unroll
      for (int r = 0; r < 4; ++r) {
        const int row = m0 + wm * 64 + i * 16 + lq * 4 + r;
        const float v = acc[i][j][r];
        if constexpr (std::is_same_v<OT, float>) {
          C[(size_t)row * ldc + col] = v;
        } else {
          C[(size_t)row * ldc + col] = f2bu(v);
        }
      }
    }
}

// ---------------------------------------------------------------------------
// out[i] = sum of 4 split-K partials (f32), float4-vectorized.
// ---------------------------------------------------------------------------
__global__ void reduce4(const float* __restrict__ q2, float* __restrict__ out) {
  const size_t i = ((size_t)blockIdx.x * 256 + threadIdx.x) * 4;
  const size_t S = (size_t)2048 * 1024;
  float4 a = *(const float4*)(q2 + i);
  const float4 b = *(const float4*)(q2 + S + i);
  const float4 c = *(const float4*)(q2 + 2 * S + i);
  const float4 d = *(const float4*)(q2 + 3 * S + i);
  a.x += b.x + c.x + d.x;
  a.y += b.y + c.y + d.y;
  a.z += b.z + c.z + d.z;
  a.w += b.w + c.w + d.w;
  *(float4*)(out + i) = a;
}

// ---------------------------------------------------------------------------
// Fused gate/up GEMM + SiLU, 128x64 tile, BK=64 two-half single-buffer
// staging (32 KB LDS). Grid (44, 16): B-tiles XCD-pinned. 2 blocks/CU
// (r14's 3/CU was confounded with the GEMM2 regression — reverted).
// ---------------------------------------------------------------------------
__global__ __launch_bounds__(256, 2)
void gateup_gemm(const u16* __restrict__ x, const u16* __restrict__ wgu,
                 u16* __restrict__ xffn) {
  constexpr int K = 1024;
  __shared__ u16 As[2 * 128 * 32];
  __shared__ u16 Bgs[2 * 64 * 32];
  __shared__ u16 Bus[2 * 64 * 32];
  const int n0 = blockIdx.x * 64;   // 44 n-tiles (fast dim -> XCD pinning)
  const int m0 = blockIdx.y * 128;  // 16 m-tiles
  const int tid = threadIdx.x;
  const int lane = tid & 63;
  const int wv = tid >> 6;
  const int wm = wv & 1, wn = wv >> 1;
  const int lr = lane & 15;
  const int lq = lane >> 4;

  f32x4 accg[4][2], accu[4][2];
#pragma unroll
  for (int i = 0; i < 4; ++i)
#pragma unroll
    for (int j = 0; j < 2; ++j) {
      accg[i][j] = (f32x4){0.f, 0.f, 0.f, 0.f};
      accu[i][j] = (f32x4){0.f, 0.f, 0.f, 0.f};
    }

  const int srow = tid >> 2;
  const int scol = (tid & 3) * 8;
  const u16* gA0 = x + (size_t)(m0 + srow) * K + scol;
  const u16* gA1 = x + (size_t)(m0 + 64 + srow) * K + scol;
  const u16* gBg = wgu + (size_t)(n0 + srow) * K + scol;
  const u16* gBu = wgu + (size_t)(INTER + n0 + srow) * K + scol;

  for (int kb = 0; kb < K; kb += 64) {
#pragma unroll
    for (int h = 0; h < 2; ++h) {
      const int kh = kb + h * 32;
      async16(gA0 + kh, As + h * 4096 + tid * 8);
      async16(gA1 + kh, As + h * 4096 + 2048 + tid * 8);
      async16(gBg + kh, Bgs + h * 2048 + tid * 8);
      async16(gBu + kh, Bus + h * 2048 + tid * 8);
    }
    __syncthreads();
#pragma unroll
    for (int h = 0; h < 2; ++h) {
      bf16x8 af[4], bg[2], bu[2];
#pragma unroll
      for (int i = 0; i < 4; ++i)
        af[i] = *(const bf16x8*)(&As[h * 4096 + (wm * 64 + i * 16 + lr) * 32 + lq * 8]);
#pragma unroll
      for (int j = 0; j < 2; ++j) {
        bg[j] = *(const bf16x8*)(&Bgs[h * 2048 + (wn * 32 + j * 16 + lr) * 32 + lq * 8]);
        bu[j] = *(const bf16x8*)(&Bus[h * 2048 + (wn * 32 + j * 16 + lr) * 32 + lq * 8]);
      }
#pragma unroll
      for (int i = 0; i < 4; ++i)
#pragma unroll
        for (int j = 0; j < 2; ++j) {
          accg[i][j] = __builtin_amdgcn_mfma_f32_16x16x32_bf16(af[i], bg[j],
                                                               accg[i][j], 0, 0, 0);
          accu[i][j] = __builtin_amdgcn_mfma_f32_16x16x32_bf16(af[i], bu[j],
                                                               accu[i][j], 0, 0, 0);
        }
    }
    __syncthreads();
  }

#pragma unroll
  for (int i = 0; i < 4; ++i)
#pragma unroll
    for (int j = 0; j < 2; ++j) {
      const int col = n0 + wn * 32 + j * 16 + lr;
#pragma unroll
      for (int r = 0; r < 4; ++r) {
        const int row = m0 + wm * 64 + i * 16 + lq * 4 + r;
        const float g = accg[i][j][r];
        const float u = accu[i][j][r];
        const float s = g / (1.f + __expf(-g));
        xffn[(size_t)row * INTER + col] = f2bu(s * u);
      }
    }
}

// ---------------------------------------------------------------------------
// Fused: sum 22 split-K partials of q (rows of 64 floats) + 9-tap shifted
// sum + offsets. Emits per-(b,k,pixel) tap records: float4 bilinear weights
// (validity folded) + int4 corner byte-offsets.
// ---------------------------------------------------------------------------
__global__ __launch_bounds__(64)
void offsets_fused(const float* __restrict__ q,   // [22][2048][64]
                   const float* __restrict__ b_metric,
                   float4* __restrict__ wrec, int4* __restrict__ orec) {
  __shared__ float lds[130 * 65];
  const int chunk = blockIdx.x;      // 0..31
  const int b = chunk >> 4;
  const int c0 = (chunk & 15) * 64;
  const int t = threadIdx.x;

  for (int v = t; v < 130 * 16; v += 64) {
    const int row = v >> 4;
    const int c4 = (v & 15) * 4;
    int pg = c0 - 33 + row;
    pg = min(max(pg, 0), 1023);
    const float* src = q + ((size_t)b * 1024 + pg) * 64 + c4;
    float4 s = *(const float4*)(src);
#pragma unroll
    for (int ks = 1; ks < 22; ++ks) {
      const float4 vv = *(const float4*)(src + (size_t)ks * 2048 * 64);
      s.x += vv.x; s.y += vv.y; s.z += vv.z; s.w += vv.w;
    }
    float* d = &lds[row * 65 + c4];
    d[0] = s.x; d[1] = s.y; d[2] = s.z; d[3] = s.w;
  }
  __syncthreads();

  const int pix = c0 + t;
  const int i = pix >> 5, j = pix & 31;
  float p[7];
#pragma unroll
  for (int o = 0; o < 7; ++o) p[o] = b_metric[o];
#pragma unroll
  for (int tap = 0; tap < 9; ++tap) {
    const int dy = tap / 3 - 1, dx = tap % 3 - 1;
    const int ii = i + dy, jj = j + dx;
    if ((unsigned)ii < 32u && (unsigned)jj < 32u) {
      const float* r = &lds[(t + 33 + dy * 32 + dx) * 65 + tap];
#pragma unroll
      for (int o = 0; o < 7; ++o) p[o] += r[o * 9];
    }
  }
  const float m00 = p[0], m01 = p[1], m10 = p[2], m11 = p[3];
  const float dry = p[4], drx = p[5];
  const float sc = tanhf(p[6]);
#pragma unroll
  for (int k = 0; k < 9; ++k) {
    const float pyk = (float)(k / 3 - 1), pxk = (float)(k % 3 - 1);
    const float offy = sc * (m00 * pyk + m01 * pxk) + dry;
    const float offx = sc * (m10 * pyk + m11 * pxk) + drx;
    const float posy = (float)i + pyk + offy;
    const float posx = (float)j + pxk + offx;
    const float y0f = floorf(posy), x0f = floorf(posx);
    const int y0 = (int)y0f, x0 = (int)x0f;
    const float ty = posy - y0f, tx = posx - x0f;
    const int y1 = y0 + 1, x1 = x0 + 1;
    const float vy0 = ((unsigned)y0 < 32u) ? 1.f : 0.f;
    const float vy1 = ((unsigned)y1 < 32u) ? 1.f : 0.f;
    const float vx0 = ((unsigned)x0 < 32u) ? 1.f : 0.f;
    const float vx1 = ((unsigned)x1 < 32u) ? 1.f : 0.f;
    float4 w;
    w.x = (1.f - ty) * (1.f - tx) * vy0 * vx0;
    w.y = (1.f - ty) * tx * vy0 * vx1;
    w.z = ty * (1.f - tx) * vy1 * vx0;
    w.w = ty * tx * vy1 * vx1;
    const int cy0 = min(max(y0, 0), 31), cy1 = min(max(y1, 0), 31);
    const int cx0 = min(max(x0, 0), 31), cx1 = min(max(x1, 0), 31);
    int4 o;
    o.x = (cy0 * 32 + cx0) * (INTER * 2);  // byte offsets within batch image
    o.y = (cy0 * 32 + cx1) * (INTER * 2);
    o.z = (cy1 * 32 + cx0) * (INTER * 2);
    o.w = (cy1 * 32 + cx1) * (INTER * 2);
    const size_t r = (((size_t)b * 9 + k) << 10) + pix;
    wrec[r] = w;
    orec[r] = o;
  }
}

// ---------------------------------------------------------------------------
// Deformable depthwise conv, 8 channels/thread, precomputed tap records,
// XCD-local pixel-range swizzle.
// ---------------------------------------------------------------------------
__global__ __launch_bounds__(256)
void deform_kernel(const u16* __restrict__ xffn,
                   const float4* __restrict__ wrec,
                   const int4* __restrict__ orec,
                   const u16* __restrict__ cwb,
                   const float* __restrict__ conv_b,
                   u16* __restrict__ gridout) {
  const unsigned bid = (blockIdx.x & 7u) * 352u + (blockIdx.x >> 3);
  const unsigned t = bid * 256 + threadIdx.x;
  const unsigned pix = t / 352u;
  const unsigned cv = t - pix * 352u;
  const int c0 = cv * 8;
  const int b = pix >> 10, l = pix & 1023;

  float acc[8];
  {
    const float4 b0 = *(const float4*)(&conv_b[c0]);
    const float4 b1 = *(const float4*)(&conv_b[c0 + 4]);
    acc[0] = b0.x; acc[1] = b0.y; acc[2] = b0.z; acc[3] = b0.w;
    acc[4] = b1.x; acc[5] = b1.y; acc[6] = b1.z; acc[7] = b1.w;
  }
  const char* xb = (const char*)xffn +
                   ((size_t)b * 1024 * INTER + c0) * sizeof(u16);
#pragma unroll
  for (int k = 0; k < 9; ++k) {
    const size_t r = (((size_t)b * 9 + k) << 10) + l;
    const float4 w = wrec[r];
    const int4 o = orec[r];
    const u16x8 v00 = *(const u16x8*)(xb + o.x);
    const u16x8 v01 = *(const u16x8*)(xb + o.y);
    const u16x8 v10 = *(const u16x8*)(xb + o.z);
    const u16x8 v11 = *(const u16x8*)(xb + o.w);
    const u16x8 cw = *(const u16x8*)(&cwb[(size_t)k * INTER + c0]);
#pragma unroll
    for (int e = 0; e < 8; ++e) {
      const float bl = w.x * bu2f(v00[e]) + w.y * bu2f(v01[e]) +
                       w.z * bu2f(v10[e]) + w.w * bu2f(v11[e]);
      acc[e] += bl * bu2f(cw[e]);
    }
  }
  u16 outv[8];
#pragma unroll
  for (int e = 0; e < 8; ++e) outv[e] = f2bu(acc[e]);
  *(uint4*)(gridout + ((size_t)b * 1024 + l) * INTER + c0) = *(uint4*)outv;
}

// ---------------------------------------------------------------------------
extern "C" void kernel_launch(void* const* d_in, const int* in_sizes, int n_in,
                              void* d_out, int out_size, void* d_ws,
                              size_t ws_size, hipStream_t stream) {
  const float* x         = (const float*)d_in[0];
  const float* w_gate_up = (const float*)d_in[1];
  const float* w_metric  = (const float*)d_in[2];
  const float* b_metric  = (const float*)d_in[3];
  const float* conv_w    = (const float*)d_in[4];
  const float* conv_b    = (const float*)d_in[5];
  const float* w_down    = (const float*)d_in[6];
  float* out = (float*)d_out;

  // Workspace (~50 MB peak). Lifetimes:
  //   gridout [0, 11.53)  bf16   step 5 -> 6
  //   q2      [12, 44)    f32    step 6 -> 7; region shared (earlier steps):
  //     xffn   [12, 23.6)  bf16  step 2 -> 5
  //     xbf    [24, 28.2)  bf16  step 1 -> 2
  //     wgubf  [28.25, 39.8) bf16 step 1 -> 2
  //     q_conv [28.25, 39.8) f32 step 3 -> 4 (22 partials, overlays wgubf)
  //     wm2    [40, 40.36) bf16  step 1 -> 3 (64 rows)
  //     cwb    [41, 41.05) bf16  step 1 -> 5
  //     wrec   [42, 42.3)  f32x4 step 4 -> 5
  //     orec   [43, 43.3)  int4  step 4 -> 5
  //   wdbf    [44, 49.8)  bf16   step 1 -> 6
  char* w = (char*)d_ws;
  u16* gridout  = (u16*)(w);
  float* q2     = (float*)(w + (12u << 20));
  u16* xffn     = (u16*)(w + (12u << 20));
  u16* xbf      = (u16*)(w + (24u << 20));
  u16* wgubf    = (u16*)(w + (28u << 20) + (256u << 10));
  float* q_conv = (float*)(w + (28u << 20) + (256u << 10));
  u16* wm2      = (u16*)(w + (40u << 20));
  u16* cwb      = (u16*)(w + (41u << 20));
  float4* wrec  = (float4*)(w + (42u << 20));
  int4* orec    = (int4*)(w + (43u << 20));
  u16* wdbf     = (u16*)(w + (44u << 20));

  // 1) fused bf16 conversions + weight repacks
  prep_all<<<6051, 256, 0, stream>>>(x, w_gate_up, w_down, w_metric, conv_w,
                                     xbf, wgubf, wdbf, wm2, cwb);
  // 2) x_ffn = silu(x@Wg^T) * (x@Wu^T)  (BK=64, grid (44,16): B-pinned)
  gateup_gemm<<<dim3(44, 16), 256, 0, stream>>>(xbf, wgubf, xffn);
  // 3) metric conv as GEMM, BN=64, split-K x22 (K=128 = 2 BK-64 iters,
  //    352 blocks = 1.4/CU vs 0.7 for x11)
  gemm_nt<64, false, float><<<dim3(16, 1, 22), 256, 0, stream>>>(
      xffn, INTER, wm2, INTER, q_conv, 2048, 64, 128);
  // 4) fused partial-sum + tap-sum + offsets -> tap records
  offsets_fused<<<32, 64, 0, stream>>>(q_conv, b_metric, wrec, orec);
  // 5) deformable depthwise conv (8 ch/thread, records, XCD-local swizzle)
  deform_kernel<<<2816, 256, 0, stream>>>(xffn, wrec, orec, cwb, conv_b,
                                          gridout);
  // 6) GEMM2 split-K x4, grid (8,16,4) n-fast: wdbf B-tiles XCD-pinned
  gemm_nt<128, true, float><<<dim3(8, 16, 4), 256, 0, stream>>>(
      gridout, INTER, wdbf, INTER, q2, 2048, 1024, 704);
  // 7) out = sum of 4 partials (deterministic, no cross-XCD atomics)
  reduce4<<<2048, 256, 0, stream>>>(q2, out);
}

// Round 16
// 195.233 us; speedup vs baseline: 1.4750x; 1.4750x over previous
//
#include <hip/hip_runtime.h>
#include <hip/hip_bf16.h>
#include <cstdint>
#include <cstddef>
#include <type_traits>

#define INTER 2816

typedef __bf16 bf16x8 __attribute__((ext_vector_type(8)));
typedef float f32x4 __attribute__((ext_vector_type(4)));
typedef unsigned short u16x8 __attribute__((ext_vector_type(8)));
using bf16 = __hip_bfloat16;
using u16 = unsigned short;

__device__ __forceinline__ u16 f2bu(float f) {
  bf16 h = __float2bfloat16(f);
  return *reinterpret_cast<u16*>(&h);
}
__device__ __forceinline__ float bu2f(u16 u) {
  bf16 h = *reinterpret_cast<bf16*>(&u);
  return __bfloat162float(h);
}

// Async global->LDS DMA, 16 B per lane (wave-uniform base + lane*16).
__device__ __forceinline__ void async16(const u16* g, u16* l) {
  __builtin_amdgcn_global_load_lds(
      (const __attribute__((address_space(1))) unsigned int*)g,
      (__attribute__((address_space(3))) unsigned int*)l, 16, 0, 0);
}

// Stage 8 contiguous f32 as bf16 (16B out).
__device__ __forceinline__ void stage8(u16* dst, const float* src) {
  const float4 a = *(const float4*)(src);
  const float4 b = *(const float4*)(src + 4);
  u16 tmp[8] = {f2bu(a.x), f2bu(a.y), f2bu(a.z), f2bu(a.w),
                f2bu(b.x), f2bu(b.y), f2bu(b.z), f2bu(b.w)};
  *(uint4*)dst = *(uint4*)tmp;
}

// ---------------------------------------------------------------------------
// Fused one-shot prep: f32->bf16 conversion of x/wgu/wd + weight repacks.
// wm2: 64 x INTER bf16 (63 metric rows + 1 zero pad). cwb: 9 x INTER bf16.
// ---------------------------------------------------------------------------
__global__ __launch_bounds__(256)
void prep_all(const float* __restrict__ x, const float* __restrict__ wgu,
              const float* __restrict__ wd, const float* __restrict__ w_metric,
              const float* __restrict__ conv_w, u16* __restrict__ xbf,
              u16* __restrict__ wgubf, u16* __restrict__ wdbf,
              u16* __restrict__ wm2, u16* __restrict__ cwb) {
  constexpr size_t S0 = (size_t)2048 * 1024;
  constexpr size_t S1 = (size_t)5632 * 1024;
  constexpr size_t S2 = (size_t)1024 * 2816;
  constexpr size_t NCONV_THREADS = (S0 + S1 + S2) / 8;  // 1343488 = 5248 blks
  const size_t t = (size_t)blockIdx.x * 256 + threadIdx.x;
  if (t < NCONV_THREADS) {
    const size_t e0 = t * 8;
    const float* src;
    u16* dst;
    size_t off;
    if (e0 < S0) {
      src = x; dst = xbf; off = e0;
    } else if (e0 < S0 + S1) {
      src = wgu; dst = wgubf; off = e0 - S0;
    } else {
      src = wd; dst = wdbf; off = e0 - S0 - S1;
    }
    stage8(dst + off, src + off);
  } else {
    const unsigned p = (unsigned)(t - NCONV_THREADS);  // 0..205567 (73 rows)
    const unsigned y = p / 2816u;                      // 0..72
    const unsigned c = p - y * 2816u;
    if (y < 64) {
      float v = 0.f;
      if (y < 63) {
        const unsigned o = y / 9, tap = y - o * 9;
        v = w_metric[((size_t)o * INTER + c) * 9 + tap];
      }
      wm2[(size_t)y * INTER + c] = f2bu(v);
    } else {
      const unsigned k = y - 64;
      cwb[(size_t)k * INTER + c] = f2bu(conv_w[(size_t)c * 9 + k]);
    }
  }
}

// ---------------------------------------------------------------------------
// NT GEMM, 128xBN tile, BK=64 staged as two BK=32 half-tiles (single buffer,
// one barrier-pair per 64 K-elements). 4 waves (2m x 2n), 16x16x32 mfma.
// NSWAP puts the n-tile on blockIdx.x for XCD pinning of B. Split-K via
// grid.z writes partial C at z*M*ldc. K must be a multiple of 64.
// ---------------------------------------------------------------------------
template <int BN, bool NSWAP, typename OT>
__global__ __launch_bounds__(256, 3)
void gemm_nt(const u16* __restrict__ A, int lda, const u16* __restrict__ Bt,
             int ldb, OT* __restrict__ C, int M, int ldc, int K) {
  constexpr int NJ = BN / 32;      // j-tiles per wave
  constexpr int BHALF = BN * 32;   // u16 per B half-tile
  __shared__ u16 As[2 * 128 * 32];
  __shared__ u16 Bs[2 * BHALF];
  const size_t koff = (size_t)blockIdx.z * K;
  A += koff;
  Bt += koff;
  C += (size_t)blockIdx.z * M * ldc;
  const int m0 = (NSWAP ? blockIdx.y : blockIdx.x) * 128;
  const int n0 = (NSWAP ? blockIdx.x : blockIdx.y) * BN;
  const int tid = threadIdx.x;
  const int lane = tid & 63;
  const int wv = tid >> 6;
  const int wm = wv & 1, wn = wv >> 1;
  const int lr = lane & 15;
  const int lq = lane >> 4;

  f32x4 acc[4][NJ];
#pragma unroll
  for (int i = 0; i < 4; ++i)
#pragma unroll
    for (int j = 0; j < NJ; ++j) acc[i][j] = (f32x4){0.f, 0.f, 0.f, 0.f};

  const int srow = tid >> 2;
  const int scol = (tid & 3) * 8;
  const u16* gA0 = A + (size_t)(m0 + srow) * lda + scol;
  const u16* gA1 = A + (size_t)(m0 + 64 + srow) * lda + scol;
  const u16* gB0 = Bt + (size_t)(n0 + srow) * ldb + scol;
  const u16* gB1 = Bt + (size_t)(n0 + 64 + srow) * ldb + scol;  // BN==128 only

  for (int kb = 0; kb < K; kb += 64) {
#pragma unroll
    for (int h = 0; h < 2; ++h) {
      const int kh = kb + h * 32;
      async16(gA0 + kh, As + h * 4096 + tid * 8);
      async16(gA1 + kh, As + h * 4096 + 2048 + tid * 8);
      async16(gB0 + kh, Bs + h * BHALF + tid * 8);
      if constexpr (BN == 128) async16(gB1 + kh, Bs + h * BHALF + 2048 + tid * 8);
    }
    __syncthreads();
#pragma unroll
    for (int h = 0; h < 2; ++h) {
      bf16x8 af[4], bfr[NJ];
#pragma unroll
      for (int i = 0; i < 4; ++i)
        af[i] = *(const bf16x8*)(&As[h * 4096 + (wm * 64 + i * 16 + lr) * 32 + lq * 8]);
#pragma unroll
      for (int j = 0; j < NJ; ++j)
        bfr[j] = *(const bf16x8*)(&Bs[h * BHALF + (wn * (BN / 2) + j * 16 + lr) * 32 + lq * 8]);
#pragma unroll
      for (int i = 0; i < 4; ++i)
#pragma unroll
        for (int j = 0; j < NJ; ++j)
          acc[i][j] = __builtin_amdgcn_mfma_f32_16x16x32_bf16(af[i], bfr[j],
                                                              acc[i][j], 0, 0, 0);
    }
    __syncthreads();
  }

#pragma unroll
  for (int i = 0; i < 4; ++i)
#pragma unroll
    for (int j = 0; j < NJ; ++j) {
      const int col = n0 + wn * (BN / 2) + j * 16 + lr;
#pragma unroll
      for (int r = 0; r < 4; ++r) {
        const int row = m0 + wm * 64 + i * 16 + lq * 4 + r;
        const float v = acc[i][j][r];
        if constexpr (std::is_same_v<OT, float>) {
          C[(size_t)row * ldc + col] = v;
        } else {
          C[(size_t)row * ldc + col] = f2bu(v);
        }
      }
    }
}

// ---------------------------------------------------------------------------
// out[i] = sum of 4 split-K partials (f32), float4-vectorized.
// ---------------------------------------------------------------------------
__global__ void reduce4(const float* __restrict__ q2, float* __restrict__ out) {
  const size_t i = ((size_t)blockIdx.x * 256 + threadIdx.x) * 4;
  const size_t S = (size_t)2048 * 1024;
  float4 a = *(const float4*)(q2 + i);
  const float4 b = *(const float4*)(q2 + S + i);
  const float4 c = *(const float4*)(q2 + 2 * S + i);
  const float4 d = *(const float4*)(q2 + 3 * S + i);
  a.x += b.x + c.x + d.x;
  a.y += b.y + c.y + d.y;
  a.z += b.z + c.z + d.z;
  a.w += b.w + c.w + d.w;
  *(float4*)(out + i) = a;
}

// ---------------------------------------------------------------------------
// Fused gate/up GEMM + SiLU, 128x64 tile, BK=64 two-half single-buffer
// staging (32 KB LDS). Grid (44, 16): B-tiles XCD-pinned. 2 blocks/CU.
// ---------------------------------------------------------------------------
__global__ __launch_bounds__(256, 2)
void gateup_gemm(const u16* __restrict__ x, const u16* __restrict__ wgu,
                 u16* __restrict__ xffn) {
  constexpr int K = 1024;
  __shared__ u16 As[2 * 128 * 32];
  __shared__ u16 Bgs[2 * 64 * 32];
  __shared__ u16 Bus[2 * 64 * 32];
  const int n0 = blockIdx.x * 64;   // 44 n-tiles (fast dim -> XCD pinning)
  const int m0 = blockIdx.y * 128;  // 16 m-tiles
  const int tid = threadIdx.x;
  const int lane = tid & 63;
  const int wv = tid >> 6;
  const int wm = wv & 1, wn = wv >> 1;
  const int lr = lane & 15;
  const int lq = lane >> 4;

  f32x4 accg[4][2], accu[4][2];
#pragma unroll
  for (int i = 0; i < 4; ++i)
#pragma unroll
    for (int j = 0; j < 2; ++j) {
      accg[i][j] = (f32x4){0.f, 0.f, 0.f, 0.f};
      accu[i][j] = (f32x4){0.f, 0.f, 0.f, 0.f};
    }

  const int srow = tid >> 2;
  const int scol = (tid & 3) * 8;
  const u16* gA0 = x + (size_t)(m0 + srow) * K + scol;
  const u16* gA1 = x + (size_t)(m0 + 64 + srow) * K + scol;
  const u16* gBg = wgu + (size_t)(n0 + srow) * K + scol;
  const u16* gBu = wgu + (size_t)(INTER + n0 + srow) * K + scol;

  for (int kb = 0; kb < K; kb += 64) {
#pragma unroll
    for (int h = 0; h < 2; ++h) {
      const int kh = kb + h * 32;
      async16(gA0 + kh, As + h * 4096 + tid * 8);
      async16(gA1 + kh, As + h * 4096 + 2048 + tid * 8);
      async16(gBg + kh, Bgs + h * 2048 + tid * 8);
      async16(gBu + kh, Bus + h * 2048 + tid * 8);
    }
    __syncthreads();
#pragma unroll
    for (int h = 0; h < 2; ++h) {
      bf16x8 af[4], bg[2], bu[2];
#pragma unroll
      for (int i = 0; i < 4; ++i)
        af[i] = *(const bf16x8*)(&As[h * 4096 + (wm * 64 + i * 16 + lr) * 32 + lq * 8]);
#pragma unroll
      for (int j = 0; j < 2; ++j) {
        bg[j] = *(const bf16x8*)(&Bgs[h * 2048 + (wn * 32 + j * 16 + lr) * 32 + lq * 8]);
        bu[j] = *(const bf16x8*)(&Bus[h * 2048 + (wn * 32 + j * 16 + lr) * 32 + lq * 8]);
      }
#pragma unroll
      for (int i = 0; i < 4; ++i)
#pragma unroll
        for (int j = 0; j < 2; ++j) {
          accg[i][j] = __builtin_amdgcn_mfma_f32_16x16x32_bf16(af[i], bg[j],
                                                               accg[i][j], 0, 0, 0);
          accu[i][j] = __builtin_amdgcn_mfma_f32_16x16x32_bf16(af[i], bu[j],
                                                               accu[i][j], 0, 0, 0);
        }
    }
    __syncthreads();
  }

#pragma unroll
  for (int i = 0; i < 4; ++i)
#pragma unroll
    for (int j = 0; j < 2; ++j) {
      const int col = n0 + wn * 32 + j * 16 + lr;
#pragma unroll
      for (int r = 0; r < 4; ++r) {
        const int row = m0 + wm * 64 + i * 16 + lq * 4 + r;
        const float g = accg[i][j][r];
        const float u = accu[i][j][r];
        const float s = g / (1.f + __expf(-g));
        xffn[(size_t)row * INTER + col] = f2bu(s * u);
      }
    }
}

// ---------------------------------------------------------------------------
// Fused: sum 11 split-K partials of q (rows of 64 floats) + 9-tap shifted
// sum + offsets -> tap records. 256 threads: all 4 waves cooperate on the
// window load (9 rows x 11 partials per thread); wave 0 computes the 64
// pixels after the barrier.
// ---------------------------------------------------------------------------
__global__ __launch_bounds__(256)
void offsets_fused(const float* __restrict__ q,   // [11][2048][64]
                   const float* __restrict__ b_metric,
                   float4* __restrict__ wrec, int4* __restrict__ orec) {
  __shared__ float lds[130 * 65];
  const int chunk = blockIdx.x;      // 0..31
  const int b = chunk >> 4;
  const int c0 = (chunk & 15) * 64;
  const int t = threadIdx.x;         // 0..255

  for (int v = t; v < 130 * 16; v += 256) {
    const int row = v >> 4;
    const int c4 = (v & 15) * 4;
    int pg = c0 - 33 + row;
    pg = min(max(pg, 0), 1023);
    const float* src = q + ((size_t)b * 1024 + pg) * 64 + c4;
    float4 s = *(const float4*)(src);
#pragma unroll
    for (int ks = 1; ks < 11; ++ks) {
      const float4 vv = *(const float4*)(src + (size_t)ks * 2048 * 64);
      s.x += vv.x; s.y += vv.y; s.z += vv.z; s.w += vv.w;
    }
    float* d = &lds[row * 65 + c4];
    d[0] = s.x; d[1] = s.y; d[2] = s.z; d[3] = s.w;
  }
  __syncthreads();
  if (t >= 64) return;

  const int pix = c0 + t;
  const int i = pix >> 5, j = pix & 31;
  float p[7];
#pragma unroll
  for (int o = 0; o < 7; ++o) p[o] = b_metric[o];
#pragma unroll
  for (int tap = 0; tap < 9; ++tap) {
    const int dy = tap / 3 - 1, dx = tap % 3 - 1;
    const int ii = i + dy, jj = j + dx;
    if ((unsigned)ii < 32u && (unsigned)jj < 32u) {
      const float* r = &lds[(t + 33 + dy * 32 + dx) * 65 + tap];
#pragma unroll
      for (int o = 0; o < 7; ++o) p[o] += r[o * 9];
    }
  }
  const float m00 = p[0], m01 = p[1], m10 = p[2], m11 = p[3];
  const float dry = p[4], drx = p[5];
  const float sc = tanhf(p[6]);
#pragma unroll
  for (int k = 0; k < 9; ++k) {
    const float pyk = (float)(k / 3 - 1), pxk = (float)(k % 3 - 1);
    const float offy = sc * (m00 * pyk + m01 * pxk) + dry;
    const float offx = sc * (m10 * pyk + m11 * pxk) + drx;
    const float posy = (float)i + pyk + offy;
    const float posx = (float)j + pxk + offx;
    const float y0f = floorf(posy), x0f = floorf(posx);
    const int y0 = (int)y0f, x0 = (int)x0f;
    const float ty = posy - y0f, tx = posx - x0f;
    const int y1 = y0 + 1, x1 = x0 + 1;
    const float vy0 = ((unsigned)y0 < 32u) ? 1.f : 0.f;
    const float vy1 = ((unsigned)y1 < 32u) ? 1.f : 0.f;
    const float vx0 = ((unsigned)x0 < 32u) ? 1.f : 0.f;
    const float vx1 = ((unsigned)x1 < 32u) ? 1.f : 0.f;
    float4 w;
    w.x = (1.f - ty) * (1.f - tx) * vy0 * vx0;
    w.y = (1.f - ty) * tx * vy0 * vx1;
    w.z = ty * (1.f - tx) * vy1 * vx0;
    w.w = ty * tx * vy1 * vx1;
    const int cy0 = min(max(y0, 0), 31), cy1 = min(max(y1, 0), 31);
    const int cx0 = min(max(x0, 0), 31), cx1 = min(max(x1, 0), 31);
    int4 o;
    o.x = (cy0 * 32 + cx0) * (INTER * 2);  // byte offsets within batch image
    o.y = (cy0 * 32 + cx1) * (INTER * 2);
    o.z = (cy1 * 32 + cx0) * (INTER * 2);
    o.w = (cy1 * 32 + cx1) * (INTER * 2);
    const size_t r = (((size_t)b * 9 + k) << 10) + pix;
    wrec[r] = w;
    orec[r] = o;
  }
}

// ---------------------------------------------------------------------------
// Deformable depthwise conv, 8 channels/thread, precomputed tap records,
// XCD-local pixel-range swizzle.
// ---------------------------------------------------------------------------
__global__ __launch_bounds__(256)
void deform_kernel(const u16* __restrict__ xffn,
                   const float4* __restrict__ wrec,
                   const int4* __restrict__ orec,
                   const u16* __restrict__ cwb,
                   const float* __restrict__ conv_b,
                   u16* __restrict__ gridout) {
  const unsigned bid = (blockIdx.x & 7u) * 352u + (blockIdx.x >> 3);
  const unsigned t = bid * 256 + threadIdx.x;
  const unsigned pix = t / 352u;
  const unsigned cv = t - pix * 352u;
  const int c0 = cv * 8;
  const int b = pix >> 10, l = pix & 1023;

  float acc[8];
  {
    const float4 b0 = *(const float4*)(&conv_b[c0]);
    const float4 b1 = *(const float4*)(&conv_b[c0 + 4]);
    acc[0] = b0.x; acc[1] = b0.y; acc[2] = b0.z; acc[3] = b0.w;
    acc[4] = b1.x; acc[5] = b1.y; acc[6] = b1.z; acc[7] = b1.w;
  }
  const char* xb = (const char*)xffn +
                   ((size_t)b * 1024 * INTER + c0) * sizeof(u16);
#pragma unroll
  for (int k = 0; k < 9; ++k) {
    const size_t r = (((size_t)b * 9 + k) << 10) + l;
    const float4 w = wrec[r];
    const int4 o = orec[r];
    const u16x8 v00 = *(const u16x8*)(xb + o.x);
    const u16x8 v01 = *(const u16x8*)(xb + o.y);
    const u16x8 v10 = *(const u16x8*)(xb + o.z);
    const u16x8 v11 = *(const u16x8*)(xb + o.w);
    const u16x8 cw = *(const u16x8*)(&cwb[(size_t)k * INTER + c0]);
#pragma unroll
    for (int e = 0; e < 8; ++e) {
      const float bl = w.x * bu2f(v00[e]) + w.y * bu2f(v01[e]) +
                       w.z * bu2f(v10[e]) + w.w * bu2f(v11[e]);
      acc[e] += bl * bu2f(cw[e]);
    }
  }
  u16 outv[8];
#pragma unroll
  for (int e = 0; e < 8; ++e) outv[e] = f2bu(acc[e]);
  *(uint4*)(gridout + ((size_t)b * 1024 + l) * INTER + c0) = *(uint4*)outv;
}

// ---------------------------------------------------------------------------
extern "C" void kernel_launch(void* const* d_in, const int* in_sizes, int n_in,
                              void* d_out, int out_size, void* d_ws,
                              size_t ws_size, hipStream_t stream) {
  const float* x         = (const float*)d_in[0];
  const float* w_gate_up = (const float*)d_in[1];
  const float* w_metric  = (const float*)d_in[2];
  const float* b_metric  = (const float*)d_in[3];
  const float* conv_w    = (const float*)d_in[4];
  const float* conv_b    = (const float*)d_in[5];
  const float* w_down    = (const float*)d_in[6];
  float* out = (float*)d_out;

  // Workspace (~50 MB peak). Lifetimes:
  //   gridout [0, 11.53)  bf16   step 5 -> 6
  //   q2      [12, 44)    f32    step 6 -> 7; region shared (earlier steps):
  //     xffn   [12, 23.6)  bf16  step 2 -> 5
  //     xbf    [24, 28.2)  bf16  step 1 -> 2
  //     wgubf  [28.25, 39.8) bf16 step 1 -> 2
  //     q_conv [28.25, 34.1) f32 step 3 -> 4 (11 partials, overlays wgubf)
  //     wm2    [40, 40.36) bf16  step 1 -> 3 (64 rows)
  //     cwb    [41, 41.05) bf16  step 1 -> 5
  //     wrec   [42, 42.3)  f32x4 step 4 -> 5
  //     orec   [43, 43.3)  int4  step 4 -> 5
  //   wdbf    [44, 49.8)  bf16   step 1 -> 6
  char* w = (char*)d_ws;
  u16* gridout  = (u16*)(w);
  float* q2     = (float*)(w + (12u << 20));
  u16* xffn     = (u16*)(w + (12u << 20));
  u16* xbf      = (u16*)(w + (24u << 20));
  u16* wgubf    = (u16*)(w + (28u << 20) + (256u << 10));
  float* q_conv = (float*)(w + (28u << 20) + (256u << 10));
  u16* wm2      = (u16*)(w + (40u << 20));
  u16* cwb      = (u16*)(w + (41u << 20));
  float4* wrec  = (float4*)(w + (42u << 20));
  int4* orec    = (int4*)(w + (43u << 20));
  u16* wdbf     = (u16*)(w + (44u << 20));

  // 1) fused bf16 conversions + weight repacks
  prep_all<<<6051, 256, 0, stream>>>(x, w_gate_up, w_down, w_metric, conv_w,
                                     xbf, wgubf, wdbf, wm2, cwb);
  // 2) x_ffn = silu(x@Wg^T) * (x@Wu^T)  (BK=64, grid (44,16): B-pinned)
  gateup_gemm<<<dim3(44, 16), 256, 0, stream>>>(xbf, wgubf, xffn);
  // 3) metric conv as GEMM, BN=64, split-K x11 (K=256 = 4 BK-64 iters)
  gemm_nt<64, false, float><<<dim3(16, 1, 11), 256, 0, stream>>>(
      xffn, INTER, wm2, INTER, q_conv, 2048, 64, 256);
  // 4) fused partial-sum + tap-sum + offsets -> tap records (256-thread load)
  offsets_fused<<<32, 256, 0, stream>>>(q_conv, b_metric, wrec, orec);
  // 5) deformable depthwise conv (8 ch/thread, records, XCD-local swizzle)
  deform_kernel<<<2816, 256, 0, stream>>>(xffn, wrec, orec, cwb, conv_b,
                                          gridout);
  // 6) GEMM2 split-K x4, grid (8,16,4) n-fast: wdbf B-tiles XCD-pinned
  gemm_nt<128, true, float><<<dim3(8, 16, 4), 256, 0, stream>>>(
      gridout, INTER, wdbf, INTER, q2, 2048, 1024, 704);
  // 7) out = sum of 4 partials (deterministic, no cross-XCD atomics)
  reduce4<<<2048, 256, 0, stream>>>(q2, out);
}